// Round 10
// baseline (851.713 us; speedup 1.0000x reference)
//
#include <hip/hip_runtime.h>

#define KTOT 65536
#define QN 16
#define DN 64
#define BN 8
#define TILE 256

// smem layout (floats) — 9216 floats = 36,864 B
#define QS_OFF 0                    // Q scaled: [16][64]                 = 1024 floats
#define R0_OFF 1024                 // K quarter region 0: [256][16]      = 4096
#define R1_OFF 5120                 // K quarter region 1: [256][16]      = 4096
                                    // R1 doubles as A: per-wave [16][64] slices (wave-private)
#define SMEM_FLOATS 9216

// async global->LDS, 16B per lane; dest = wave-uniform base + lane*16
__device__ __forceinline__ void gload_lds16(const float* g, float* l)
{
    __builtin_amdgcn_global_load_lds(
        (const __attribute__((address_space(1))) void*)g,
        (__attribute__((address_space(3))) void*)l, 16, 0, 0);
}

// Counted wait. "memory" clobber = compiler fence: no memory op crosses it, so the
// vmcnt ledger is exact. sched_barrier(0) stops reg-only ops hoisting (rule #18).
// Safe-conservative: vmcnt retires in order; waiting to <=N guarantees every op with
// >=N younger memory ops has retired.
#define WAIT_VM(N)  do { asm volatile("s_waitcnt vmcnt(" #N ")" ::: "memory");      \
                         __builtin_amdgcn_sched_barrier(0); } while (0)
#define LGKM0()     do { asm volatile("s_waitcnt lgkmcnt(0)" ::: "memory");         \
                         __builtin_amdgcn_sched_barrier(0); } while (0)

// WAVE-PRIVATE staging (verified rounds 7/9): wave wv stages ITS OWN rows 64wv..64wv+63
// of one K quarter (16 float cols; qo4 = quarter*4 in float4 units); exactly 4 gload_lds.
// Source pre-swizzled: global col = (lane&3) ^ ((row>>1)&3); read applies same XOR.
#define STAGE_WV(RX, kb4, qo4)                                                      \
    {                                                                               \
        _Pragma("unroll")                                                           \
        for (int j = 0; j < 4; ++j) {                                               \
            const int r_ = (wv << 6) + (j << 4) + (lane >> 2);                      \
            const int p_ = (lane & 3) ^ ((r_ >> 1) & 3);                            \
            gload_lds16((const float*)((kb4) + r_ * 16 + (qo4) + p_),               \
                        (float*)(((float4*)&smem[RX]) + ((wv << 8) + (j << 6) + lane))); \
        }                                                                           \
    }

// dot quarter qt from region RX: thread owns row tid; Q broadcast from LDS
#define DOT_Q(qt, RX)                                                               \
    {                                                                               \
        _Pragma("unroll")                                                           \
        for (int cc = 0; cc < 4; ++cc) {                                            \
            const float4 kv = ((const float4*)&smem[RX])[tid * 4 + (cc ^ fr)];      \
            _Pragma("unroll")                                                       \
            for (int q = 0; q < QN; ++q) {                                          \
                const float4 qv = *reinterpret_cast<const float4*>(                 \
                    &smem[QS_OFF + q * DN + (qt) * 16 + cc * 4]);                   \
                s[q] = fmaf(kv.x, qv.x, s[q]);                                      \
                s[q] = fmaf(kv.y, qv.y, s[q]);                                      \
                s[q] = fmaf(kv.z, qv.z, s[q]);                                      \
                s[q] = fmaf(kv.w, qv.w, s[q]);                                      \
            }                                                                       \
        }                                                                           \
    }

// ------------- Fused: QK^T + softmax(Q) + attn write + PV partials + norm partials ----------
// Round-10 schedule (vs round 9's 84us): next-tile q0' staging HOISTED from post-PV to
// post-dot2 — it now has dot3+softmax+PV (~2000cy) of cover instead of ZERO; q1' stays
// post-PV (aliases A) and is covered by next tile's dot0. ntiles=4 so 3/4 of tiles enjoy
// the covered pipeline (was 1/2) and the cold prologue is amortized 2x.
__global__ __launch_bounds__(256, 3) void fused_attn(
    const float* __restrict__ query, const float* __restrict__ key,
    const float* __restrict__ value, float* __restrict__ attn,
    float* __restrict__ normp, float* __restrict__ upart,
    int NCH, int ntiles)
{
    __shared__ float smem[SMEM_FLOATS];
    const int b    = blockIdx.y;
    const int c    = blockIdx.x;
    const int tid  = threadIdx.x;
    const int wv   = tid >> 6;
    const int lane = tid & 63;
    const int chunk = ntiles * TILE;
    const int fr   = (tid >> 1) & 3;
    const int AW   = R1_OFF + wv * (QN * 64);   // A: own 4KB slice of R1

    // Q -> LDS (scaled), ONE barrier; stages issued after it are never drained again
    {
        float4 qv = reinterpret_cast<const float4*>(query + (size_t)b * QN * DN)[tid];
        qv.x *= 0.125f; qv.y *= 0.125f; qv.z *= 0.125f; qv.w *= 0.125f;
        reinterpret_cast<float4*>(&smem[QS_OFF])[tid] = qv;
    }
    __syncthreads();

    {
        const float4* kb4 = reinterpret_cast<const float4*>(
            key + ((size_t)b * KTOT + c * chunk) * DN);
        STAGE_WV(R0_OFF, kb4, 0);   // tile0 q0
        STAGE_WV(R1_OFF, kb4, 4);   // tile0 q1
        __builtin_amdgcn_sched_barrier(0);
    }

    float U[QN], nacc[QN];
    #pragma unroll
    for (int q = 0; q < QN; ++q) { U[q] = 0.f; nacc[q] = 0.f; }

    for (int t = 0; t < ntiles; ++t) {
        const int krow0 = c * chunk + t * TILE;
        const float4* kb4  = reinterpret_cast<const float4*>(
            key + ((size_t)b * KTOT + krow0) * DN);
        const float4* kb4n = kb4 + TILE * 16;                         // next tile
        const float*  vptr = value + ((size_t)b * KTOT + krow0 + wv * 64) * DN + lane;

        float s[QN];
        #pragma unroll
        for (int q = 0; q < QN; ++q) s[q] = 0.f;

        // ledger: q0 has >=24 younger ops (stores/vb/q1) -> WAIT(4) guarantees it retired
        WAIT_VM(4);                                                   // q0 ready
        DOT_Q(0, R0_OFF);
        LGKM0(); STAGE_WV(R0_OFF, kb4, 8);                            // q2 -> R0
        __builtin_amdgcn_sched_barrier(0);

        WAIT_VM(4);                                                   // q1 ready (younger: q2=4)
        DOT_Q(1, R1_OFF);
        LGKM0(); STAGE_WV(R1_OFF, kb4, 12);                           // q3 -> R1
        __builtin_amdgcn_sched_barrier(0);

        WAIT_VM(4);                                                   // q2 ready (younger: q3=4)
        DOT_Q(2, R0_OFF);

        // HOISTED: next tile's q0' -> R0 (R0 free: own dot-q2 reads retired via LGKM0).
        // Covered by dot3 + softmax + PV.
        const bool more = (t + 1 < ntiles);
        LGKM0();
        if (more) { STAGE_WV(R0_OFF, kb4n, 0); __builtin_amdgcn_sched_barrier(0); }

        // V batch 0 (rides through dot q3 + softmax)
        float va[8];
        #pragma unroll
        for (int i = 0; i < 8; ++i) va[i] = vptr[(size_t)i * DN];
        __builtin_amdgcn_sched_barrier(0);
        // q3 ready: younger ops = q0'(4 if more) + va(8)
        if (more) { WAIT_VM(12); } else { WAIT_VM(8); }
        DOT_Q(3, R1_OFF);

        // ---- softmax over the 16 queries (thread-local, k = krow0 + tid) ----
        float m = s[0];
        #pragma unroll
        for (int q = 1; q < QN; ++q) m = fmaxf(m, s[q]);
        float sum = 0.f;
        #pragma unroll
        for (int q = 0; q < QN; ++q) { s[q] = __expf(s[q] - m); sum += s[q]; }
        const float inv = 1.0f / sum;
        {
            float* ab = attn + (size_t)b * QN * KTOT + krow0 + tid;
            #pragma unroll
            for (int q = 0; q < QN; ++q) {
                const float a = s[q] * inv;
                __builtin_nontemporal_store(a, ab + (size_t)q * KTOT);
                smem[AW + q * 64 + lane] = a;        // own slice; dot-q3 reads already retired
                nacc[q] += a;
            }
        }

        // ---- PV: U[q][lane=d] += a[q][k] * v[k][d]; wave owns 64 k-rows ----
        #pragma unroll 1
        for (int kk = 0; kk < 64; kk += 8) {
            float vb[8];
            const int nxt = kk + 8;
            if (nxt < 64) {
                #pragma unroll
                for (int i = 0; i < 8; ++i) vb[i] = vptr[(size_t)(nxt + i) * DN];
            }
            #pragma unroll
            for (int kq = 0; kq < 8; kq += 4) {
                #pragma unroll
                for (int q = 0; q < QN; ++q) {
                    const float4 av = *reinterpret_cast<const float4*>(
                        &smem[AW + q * 64 + kk + kq]);              // uniform broadcast
                    U[q] = fmaf(av.x, va[kq + 0], U[q]);
                    U[q] = fmaf(av.y, va[kq + 1], U[q]);
                    U[q] = fmaf(av.z, va[kq + 2], U[q]);
                    U[q] = fmaf(av.w, va[kq + 3], U[q]);
                }
            }
            #pragma unroll
            for (int i = 0; i < 8; ++i) va[i] = vb[i];
        }

        // q1' -> R1 at PV end (A reads done via LGKM0); covered by next tile's dot0
        if (more) {
            LGKM0();
            STAGE_WV(R1_OFF, kb4n, 4);
            __builtin_amdgcn_sched_barrier(0);
        }
    }

    // ---- block reductions: U across 4 waves (R0 region), nacc (R1 region) ----
    __syncthreads();                                   // full drain (outside main loop)
    #pragma unroll
    for (int q = 0; q < QN; ++q)
        smem[R0_OFF + (wv * QN + q) * DN + lane] = U[q];
    #pragma unroll
    for (int q = 0; q < QN; ++q) {
        #pragma unroll
        for (int off = 1; off < 64; off <<= 1)
            nacc[q] += __shfl_xor(nacc[q], off, 64);
    }
    if (lane == 0) {
        #pragma unroll
        for (int q = 0; q < QN; ++q) smem[R1_OFF + wv * QN + q] = nacc[q];
    }
    __syncthreads();

    {
        const int q = tid >> 4, d0 = (tid & 15) * 4;
        const float4 r0 = *reinterpret_cast<const float4*>(&smem[R0_OFF + (0 * QN + q) * DN + d0]);
        const float4 r1 = *reinterpret_cast<const float4*>(&smem[R0_OFF + (1 * QN + q) * DN + d0]);
        const float4 r2 = *reinterpret_cast<const float4*>(&smem[R0_OFF + (2 * QN + q) * DN + d0]);
        const float4 r3 = *reinterpret_cast<const float4*>(&smem[R0_OFF + (3 * QN + q) * DN + d0]);
        float4 rs;
        rs.x = r0.x + r1.x + r2.x + r3.x;
        rs.y = r0.y + r1.y + r2.y + r3.y;
        rs.z = r0.z + r1.z + r2.z + r3.z;
        rs.w = r0.w + r1.w + r2.w + r3.w;
        *reinterpret_cast<float4*>(
            &upart[(((size_t)b * NCH + c) * QN + q) * DN + d0]) = rs;
        if (tid < QN)
            normp[((size_t)b * NCH + c) * QN + tid] =
                smem[R1_OFF + tid] + smem[R1_OFF + QN + tid] +
                smem[R1_OFF + 2 * QN + tid] + smem[R1_OFF + 3 * QN + tid];
    }
}

// ------------- Finalize: out[b][q][d] = sum_c U / (sum_c norm + eps); grid (8,16) -----------
__global__ __launch_bounds__(256) void k3_fin(
    const float* __restrict__ upart, const float* __restrict__ normp,
    float* __restrict__ out, int NCH)
{
    const int b = blockIdx.x, q = blockIdx.y;
    const int tid = threadIdx.x;
    const int wv = tid >> 6, lane = tid & 63;

    float nv = 0.f;
    for (int c = tid; c < NCH; c += 256)
        nv += normp[((size_t)b * NCH + c) * QN + q];
    #pragma unroll
    for (int off = 1; off < 64; off <<= 1) nv += __shfl_xor(nv, off, 64);
    __shared__ float nred[4];
    if (lane == 0) nred[wv] = nv;

    float acc = 0.f;
    for (int c = wv; c < NCH; c += 4)
        acc += upart[(((size_t)b * NCH + c) * QN + q) * DN + lane];
    __shared__ float ured[4][DN];
    ured[wv][lane] = acc;
    __syncthreads();

    if (tid < DN) {
        const float n   = nred[0] + nred[1] + nred[2] + nred[3];
        const float inv = 1.0f / (n + 1e-8f);
        const float u   = ured[0][tid] + ured[1][tid] + ured[2][tid] + ured[3][tid];
        out[((size_t)b * QN + q) * DN + tid] = u * inv;
    }
}

extern "C" void kernel_launch(void* const* d_in, const int* in_sizes, int n_in,
                              void* d_out, int out_size, void* d_ws, size_t ws_size,
                              hipStream_t stream)
{
    const float* query = (const float*)d_in[0];
    const float* key   = (const float*)d_in[1];
    const float* value = (const float*)d_in[2];

    float* out  = (float*)d_out;                          // [8,16,64]
    float* attn = (float*)d_out + (size_t)BN * QN * DN;   // [8,1,16,65536]

    int NCH = 64;                                         // 512 blocks; ntiles=4 -> 3/4 tiles
    while (NCH > 8 && (size_t)BN * NCH * QN * (DN + 1) * 4 > ws_size) NCH >>= 1;
    const int ntiles = (KTOT / NCH) / TILE;               // fully pipeline-covered

    float* normp = (float*)d_ws;                          // [8][NCH][16]
    float* upart = (float*)d_ws + (size_t)BN * NCH * QN;  // [8][NCH][16][64]

    fused_attn<<<dim3(NCH, BN), 256, 0, stream>>>(query, key, value, attn,
                                                  normp, upart, NCH, ntiles);
    k3_fin   <<<dim3(BN, QN), 256, 0, stream>>>(upart, normp, out, NCH);
}

// Round 11
// 90.136 us; speedup vs baseline: 9.4492x; 9.4492x over previous
//
#include <hip/hip_runtime.h>

#define KTOT 65536
#define QN 16
#define DN 64
#define BN 8
#define TILE 256

// smem layout (floats) — 9216 floats = 36,864 B
#define QS_OFF 0                    // Q scaled: [16][64]                 = 1024 floats
#define R0_OFF 1024                 // K quarter region 0: [256][16]      = 4096
#define R1_OFF 5120                 // K quarter region 1: [256][16]      = 4096
                                    // R1 doubles as A: per-wave [16][64] slices (wave-private)
#define SMEM_FLOATS 9216

// async global->LDS, 16B per lane; dest = wave-uniform base + lane*16
__device__ __forceinline__ void gload_lds16(const float* g, float* l)
{
    __builtin_amdgcn_global_load_lds(
        (const __attribute__((address_space(1))) void*)g,
        (__attribute__((address_space(3))) void*)l, 16, 0, 0);
}

// Counted wait. "memory" clobber = compiler fence (exact vmcnt ledger);
// sched_barrier(0) stops reg-only hoisting (rule #18).
// ROUND-10 LESSON: these must only appear in STRAIGHT-LINE code — conditional
// stage/wait blocks in the hot loop wrecked regalloc (1.5 GB scratch writes).
#define WAIT_VM(N)  do { asm volatile("s_waitcnt vmcnt(" #N ")" ::: "memory");      \
                         __builtin_amdgcn_sched_barrier(0); } while (0)
#define LGKM0()     do { asm volatile("s_waitcnt lgkmcnt(0)" ::: "memory");         \
                         __builtin_amdgcn_sched_barrier(0); } while (0)

// WAVE-PRIVATE staging (verified r7/r9): wave wv stages ITS OWN rows 64wv..64wv+63
// of one K quarter (16 float cols; qo4 = quarter*4 in float4 units); exactly 4 gload_lds.
// Source pre-swizzled: global col = (lane&3) ^ ((row>>1)&3); read applies same XOR.
#define STAGE_WV(RX, kb4, qo4)                                                      \
    {                                                                               \
        _Pragma("unroll")                                                           \
        for (int j = 0; j < 4; ++j) {                                               \
            const int r_ = (wv << 6) + (j << 4) + (lane >> 2);                      \
            const int p_ = (lane & 3) ^ ((r_ >> 1) & 3);                            \
            gload_lds16((const float*)((kb4) + r_ * 16 + (qo4) + p_),               \
                        (float*)(((float4*)&smem[RX]) + ((wv << 8) + (j << 6) + lane))); \
        }                                                                           \
    }

// dot quarter qt from region RX: thread owns row tid; Q broadcast from LDS
#define DOT_Q(qt, RX)                                                               \
    {                                                                               \
        _Pragma("unroll")                                                           \
        for (int cc = 0; cc < 4; ++cc) {                                            \
            const float4 kv = ((const float4*)&smem[RX])[tid * 4 + (cc ^ fr)];      \
            _Pragma("unroll")                                                       \
            for (int q = 0; q < QN; ++q) {                                          \
                const float4 qv = *reinterpret_cast<const float4*>(                 \
                    &smem[QS_OFF + q * DN + (qt) * 16 + cc * 4]);                   \
                s[q] = fmaf(kv.x, qv.x, s[q]);                                      \
                s[q] = fmaf(kv.y, qv.y, s[q]);                                      \
                s[q] = fmaf(kv.z, qv.z, s[q]);                                      \
                s[q] = fmaf(kv.w, qv.w, s[q]);                                      \
            }                                                                       \
        }                                                                           \
    }

// ------------- Fused: QK^T + softmax(Q) + attn write + PV partials + norm partials ----------
// Round-11 = round 9 (84us, proven) + BRANCHLESS hoist of next-tile q0' staging to
// post-dot2 (cover: dot3+softmax+PV ~2000cy instead of zero). Last tile re-stages its own
// quarters via a clamped pointer SELECT (uniform s_cselect, no branch) — harmless and keeps
// the loop body straight-line (round-10 lesson). Constant WAIT_VM(12) before dot3.
__global__ __launch_bounds__(256, 3) void fused_attn(
    const float* __restrict__ query, const float* __restrict__ key,
    const float* __restrict__ value, float* __restrict__ attn,
    float* __restrict__ normp, float* __restrict__ upart,
    int NCH, int ntiles)
{
    __shared__ float smem[SMEM_FLOATS];
    const int b    = blockIdx.y;
    const int c    = blockIdx.x;
    const int tid  = threadIdx.x;
    const int wv   = tid >> 6;
    const int lane = tid & 63;
    const int chunk = ntiles * TILE;
    const int fr   = (tid >> 1) & 3;
    const int AW   = R1_OFF + wv * (QN * 64);   // A: own 4KB slice of R1

    // Q -> LDS (scaled), ONE barrier; stages issued after it are never drained again
    {
        float4 qv = reinterpret_cast<const float4*>(query + (size_t)b * QN * DN)[tid];
        qv.x *= 0.125f; qv.y *= 0.125f; qv.z *= 0.125f; qv.w *= 0.125f;
        reinterpret_cast<float4*>(&smem[QS_OFF])[tid] = qv;
    }
    __syncthreads();

    {
        const float4* kb4 = reinterpret_cast<const float4*>(
            key + ((size_t)b * KTOT + c * chunk) * DN);
        STAGE_WV(R0_OFF, kb4, 0);   // tile0 q0
        STAGE_WV(R1_OFF, kb4, 4);   // tile0 q1
        __builtin_amdgcn_sched_barrier(0);
    }

    float U[QN], nacc[QN];
    #pragma unroll
    for (int q = 0; q < QN; ++q) { U[q] = 0.f; nacc[q] = 0.f; }

    for (int t = 0; t < ntiles; ++t) {
        const int krow0 = c * chunk + t * TILE;
        const float4* kb4  = reinterpret_cast<const float4*>(
            key + ((size_t)b * KTOT + krow0) * DN);
        // next-tile base, CLAMPED (uniform select, no branch): last tile re-stages itself
        const float4* kb4n = kb4 + ((t + 1 < ntiles) ? TILE * 16 : 0);
        const float*  vptr = value + ((size_t)b * KTOT + krow0 + wv * 64) * DN + lane;

        float s[QN];
        #pragma unroll
        for (int q = 0; q < QN; ++q) s[q] = 0.f;

        // ledger: only q1'(4, youngest) may remain -> q0' (hoisted last tile) retired
        WAIT_VM(4);
        DOT_Q(0, R0_OFF);
        LGKM0(); STAGE_WV(R0_OFF, kb4, 8);                            // q2 -> R0
        __builtin_amdgcn_sched_barrier(0);

        WAIT_VM(4);                                                   // q1 retired (q2 may remain)
        DOT_Q(1, R1_OFF);
        LGKM0(); STAGE_WV(R1_OFF, kb4, 12);                           // q3 -> R1
        __builtin_amdgcn_sched_barrier(0);

        WAIT_VM(4);                                                   // q2 retired (q3 may remain)
        DOT_Q(2, R0_OFF);

        // HOISTED next-tile q0' -> R0 (own dot-q2 reads retired via LGKM0);
        // covered by dot3 + softmax + PV. Unconditional (clamped pointer).
        LGKM0(); STAGE_WV(R0_OFF, kb4n, 0);
        __builtin_amdgcn_sched_barrier(0);

        // V batch 0 (rides through dot q3 + softmax)
        float va[8];
        #pragma unroll
        for (int i = 0; i < 8; ++i) va[i] = vptr[(size_t)i * DN];
        __builtin_amdgcn_sched_barrier(0);
        WAIT_VM(12);                                                  // q3 retired (q0'4+va8 younger)
        DOT_Q(3, R1_OFF);

        // ---- softmax over the 16 queries (thread-local, k = krow0 + tid) ----
        float m = s[0];
        #pragma unroll
        for (int q = 1; q < QN; ++q) m = fmaxf(m, s[q]);
        float sum = 0.f;
        #pragma unroll
        for (int q = 0; q < QN; ++q) { s[q] = __expf(s[q] - m); sum += s[q]; }
        const float inv = 1.0f / sum;
        {
            float* ab = attn + (size_t)b * QN * KTOT + krow0 + tid;
            #pragma unroll
            for (int q = 0; q < QN; ++q) {
                const float a = s[q] * inv;
                __builtin_nontemporal_store(a, ab + (size_t)q * KTOT);
                smem[AW + q * 64 + lane] = a;        // own slice; dot-q3 reads already retired
                nacc[q] += a;
            }
        }

        // ---- PV: U[q][lane=d] += a[q][k] * v[k][d]; wave owns 64 k-rows ----
        #pragma unroll 1
        for (int kk = 0; kk < 64; kk += 8) {
            float vb[8];
            const int nxt = kk + 8;
            if (nxt < 64) {
                #pragma unroll
                for (int i = 0; i < 8; ++i) vb[i] = vptr[(size_t)(nxt + i) * DN];
            }
            #pragma unroll
            for (int kq = 0; kq < 8; kq += 4) {
                #pragma unroll
                for (int q = 0; q < QN; ++q) {
                    const float4 av = *reinterpret_cast<const float4*>(
                        &smem[AW + q * 64 + kk + kq]);              // uniform broadcast
                    U[q] = fmaf(av.x, va[kq + 0], U[q]);
                    U[q] = fmaf(av.y, va[kq + 1], U[q]);
                    U[q] = fmaf(av.z, va[kq + 2], U[q]);
                    U[q] = fmaf(av.w, va[kq + 3], U[q]);
                }
            }
            #pragma unroll
            for (int i = 0; i < 8; ++i) va[i] = vb[i];
        }

        // next-tile q1' -> R1 at PV end (A reads retired via LGKM0); covered by next dot0.
        // Unconditional (clamped pointer): straight-line body.
        LGKM0(); STAGE_WV(R1_OFF, kb4n, 4);
        __builtin_amdgcn_sched_barrier(0);
    }

    // ---- block reductions: U across 4 waves (R0 region), nacc (R1 region) ----
    __syncthreads();                                   // full drain (stray last-tile stages too)
    #pragma unroll
    for (int q = 0; q < QN; ++q)
        smem[R0_OFF + (wv * QN + q) * DN + lane] = U[q];
    #pragma unroll
    for (int q = 0; q < QN; ++q) {
        #pragma unroll
        for (int off = 1; off < 64; off <<= 1)
            nacc[q] += __shfl_xor(nacc[q], off, 64);
    }
    if (lane == 0) {
        #pragma unroll
        for (int q = 0; q < QN; ++q) smem[R1_OFF + wv * QN + q] = nacc[q];
    }
    __syncthreads();

    {
        const int q = tid >> 4, d0 = (tid & 15) * 4;
        const float4 r0 = *reinterpret_cast<const float4*>(&smem[R0_OFF + (0 * QN + q) * DN + d0]);
        const float4 r1 = *reinterpret_cast<const float4*>(&smem[R0_OFF + (1 * QN + q) * DN + d0]);
        const float4 r2 = *reinterpret_cast<const float4*>(&smem[R0_OFF + (2 * QN + q) * DN + d0]);
        const float4 r3 = *reinterpret_cast<const float4*>(&smem[R0_OFF + (3 * QN + q) * DN + d0]);
        float4 rs;
        rs.x = r0.x + r1.x + r2.x + r3.x;
        rs.y = r0.y + r1.y + r2.y + r3.y;
        rs.z = r0.z + r1.z + r2.z + r3.z;
        rs.w = r0.w + r1.w + r2.w + r3.w;
        *reinterpret_cast<float4*>(
            &upart[(((size_t)b * NCH + c) * QN + q) * DN + d0]) = rs;
        if (tid < QN)
            normp[((size_t)b * NCH + c) * QN + tid] =
                smem[R1_OFF + tid] + smem[R1_OFF + QN + tid] +
                smem[R1_OFF + 2 * QN + tid] + smem[R1_OFF + 3 * QN + tid];
    }
}

// ------------- Finalize: out[b][q][d] = sum_c U / (sum_c norm + eps); grid (8,16) -----------
__global__ __launch_bounds__(256) void k3_fin(
    const float* __restrict__ upart, const float* __restrict__ normp,
    float* __restrict__ out, int NCH)
{
    const int b = blockIdx.x, q = blockIdx.y;
    const int tid = threadIdx.x;
    const int wv = tid >> 6, lane = tid & 63;

    float nv = 0.f;
    for (int c = tid; c < NCH; c += 256)
        nv += normp[((size_t)b * NCH + c) * QN + q];
    #pragma unroll
    for (int off = 1; off < 64; off <<= 1) nv += __shfl_xor(nv, off, 64);
    __shared__ float nred[4];
    if (lane == 0) nred[wv] = nv;

    float acc = 0.f;
    for (int c = wv; c < NCH; c += 4)
        acc += upart[(((size_t)b * NCH + c) * QN + q) * DN + lane];
    __shared__ float ured[4][DN];
    ured[wv][lane] = acc;
    __syncthreads();

    if (tid < DN) {
        const float n   = nred[0] + nred[1] + nred[2] + nred[3];
        const float inv = 1.0f / (n + 1e-8f);
        const float u   = ured[0][tid] + ured[1][tid] + ured[2][tid] + ured[3][tid];
        out[((size_t)b * QN + q) * DN + tid] = u * inv;
    }
}

extern "C" void kernel_launch(void* const* d_in, const int* in_sizes, int n_in,
                              void* d_out, int out_size, void* d_ws, size_t ws_size,
                              hipStream_t stream)
{
    const float* query = (const float*)d_in[0];
    const float* key   = (const float*)d_in[1];
    const float* value = (const float*)d_in[2];

    float* out  = (float*)d_out;                          // [8,16,64]
    float* attn = (float*)d_out + (size_t)BN * QN * DN;   // [8,1,16,65536]

    int NCH = 128;                                        // 1024 blocks (round-9 proven)
    while (NCH > 8 && (size_t)BN * NCH * QN * (DN + 1) * 4 > ws_size) NCH >>= 1;
    const int ntiles = (KTOT / NCH) / TILE;

    float* normp = (float*)d_ws;                          // [8][NCH][16]
    float* upart = (float*)d_ws + (size_t)BN * NCH * QN;  // [8][NCH][16][64]

    fused_attn<<<dim3(NCH, BN), 256, 0, stream>>>(query, key, value, attn,
                                                  normp, upart, NCH, ntiles);
    k3_fin   <<<dim3(BN, QN), 256, 0, stream>>>(upart, normp, out, NCH);
}

// Round 12
// 83.356 us; speedup vs baseline: 10.2178x; 1.0813x over previous
//
#include <hip/hip_runtime.h>

#define KTOT 65536
#define QN 16
#define DN 64
#define BN 8
#define TILE 256

// smem layout (floats) — 9216 floats = 36,864 B
#define QS_OFF 0                    // Q scaled: [16][64]                 = 1024 floats
#define R0_OFF 1024                 // K quarter region 0: [256][16]      = 4096
#define R1_OFF 5120                 // K quarter region 1: [256][16]      = 4096
                                    // R1 doubles as A: per-wave [16][64] slices (wave-private)
#define SMEM_FLOATS 9216

// async global->LDS, 16B per lane; dest = wave-uniform base + lane*16
__device__ __forceinline__ void gload_lds16(const float* g, float* l)
{
    __builtin_amdgcn_global_load_lds(
        (const __attribute__((address_space(1))) void*)g,
        (__attribute__((address_space(3))) void*)l, 16, 0, 0);
}

// Counted wait. "memory" clobber = compiler fence (exact vmcnt ledger);
// sched_barrier(0) stops reg-only hoisting (rule #18). Straight-line use only (r10 lesson).
#define WAIT_VM(N)  do { asm volatile("s_waitcnt vmcnt(" #N ")" ::: "memory");      \
                         __builtin_amdgcn_sched_barrier(0); } while (0)
#define LGKM0()     do { asm volatile("s_waitcnt lgkmcnt(0)" ::: "memory");         \
                         __builtin_amdgcn_sched_barrier(0); } while (0)

// WAVE-PRIVATE staging (verified r7/r9): wave wv stages ITS OWN rows 64wv..64wv+63
// of one K quarter (16 float cols; qo4 = quarter*4 in float4 units); exactly 4 gload_lds.
// Source pre-swizzled: global col = (lane&3) ^ ((row>>1)&3); read applies same XOR.
#define STAGE_WV(RX, kb4, qo4)                                                      \
    {                                                                               \
        _Pragma("unroll")                                                           \
        for (int j = 0; j < 4; ++j) {                                               \
            const int r_ = (wv << 6) + (j << 4) + (lane >> 2);                      \
            const int p_ = (lane & 3) ^ ((r_ >> 1) & 3);                            \
            gload_lds16((const float*)((kb4) + r_ * 16 + (qo4) + p_),               \
                        (float*)(((float4*)&smem[RX]) + ((wv << 8) + (j << 6) + lane))); \
        }                                                                           \
    }

// dot quarter qt from region RX: thread owns row tid; Q broadcast from LDS
#define DOT_Q(qt, RX)                                                               \
    {                                                                               \
        _Pragma("unroll")                                                           \
        for (int cc = 0; cc < 4; ++cc) {                                            \
            const float4 kv = ((const float4*)&smem[RX])[tid * 4 + (cc ^ fr)];      \
            _Pragma("unroll")                                                       \
            for (int q = 0; q < QN; ++q) {                                          \
                const float4 qv = *reinterpret_cast<const float4*>(                 \
                    &smem[QS_OFF + q * DN + (qt) * 16 + cc * 4]);                   \
                s[q] = fmaf(kv.x, qv.x, s[q]);                                      \
                s[q] = fmaf(kv.y, qv.y, s[q]);                                      \
                s[q] = fmaf(kv.z, qv.z, s[q]);                                      \
                s[q] = fmaf(kv.w, qv.w, s[q]);                                      \
            }                                                                       \
        }                                                                           \
    }

// ------------- Fused: QK^T + softmax(Q) + attn write + PV partials ----------
// Round-12 = round 9's proven 84us schedule, with the norm accumulator (nacc[16] + its
// shfl-reduce + normp write) REMOVED — the norm is recomputed in k3_fin from the attn
// matrix we already write to global. Peak live set drops ~80 -> ~60 regs, so
// __launch_bounds__(256,4) (round-4's 64-VGPR codegen) now fits SPILL-FREE, unlocking
// the 40% occupancy round 4 demonstrated (13 waves/CU vs 8) without round 4's scratch.
__global__ __launch_bounds__(256, 4) void fused_attn(
    const float* __restrict__ query, const float* __restrict__ key,
    const float* __restrict__ value, float* __restrict__ attn,
    float* __restrict__ upart, int NCH, int ntiles)
{
    __shared__ float smem[SMEM_FLOATS];
    const int b    = blockIdx.y;
    const int c    = blockIdx.x;
    const int tid  = threadIdx.x;
    const int wv   = tid >> 6;
    const int lane = tid & 63;
    const int chunk = ntiles * TILE;
    const int fr   = (tid >> 1) & 3;
    const int AW   = R1_OFF + wv * (QN * 64);   // A: own 4KB slice of R1

    // Q -> LDS (scaled), ONE barrier; stages issued after it are never drained again
    {
        float4 qv = reinterpret_cast<const float4*>(query + (size_t)b * QN * DN)[tid];
        qv.x *= 0.125f; qv.y *= 0.125f; qv.z *= 0.125f; qv.w *= 0.125f;
        reinterpret_cast<float4*>(&smem[QS_OFF])[tid] = qv;
    }
    __syncthreads();

    {
        const float4* kb4 = reinterpret_cast<const float4*>(
            key + ((size_t)b * KTOT + c * chunk) * DN);
        STAGE_WV(R0_OFF, kb4, 0);   // tile0 q0
        STAGE_WV(R1_OFF, kb4, 4);   // tile0 q1
        __builtin_amdgcn_sched_barrier(0);
    }

    float U[QN];
    #pragma unroll
    for (int q = 0; q < QN; ++q) U[q] = 0.f;

    for (int t = 0; t < ntiles; ++t) {
        const int krow0 = c * chunk + t * TILE;
        const float4* kb4  = reinterpret_cast<const float4*>(
            key + ((size_t)b * KTOT + krow0) * DN);
        const float4* kb4n = kb4 + TILE * 16;                         // next tile
        const float*  vptr = value + ((size_t)b * KTOT + krow0 + wv * 64) * DN + lane;

        float s[QN];
        #pragma unroll
        for (int q = 0; q < QN; ++q) s[q] = 0.f;

        // ledger (wave-local, r9-proven): top of tile outstanding = stores(old)+q0(4)+q1(4)
        WAIT_VM(4);                                                   // q0 ready
        DOT_Q(0, R0_OFF);
        LGKM0(); STAGE_WV(R0_OFF, kb4, 8);                            // q2 -> R0
        __builtin_amdgcn_sched_barrier(0);

        WAIT_VM(4);                                                   // q1 ready (q2 may remain)
        DOT_Q(1, R1_OFF);
        LGKM0(); STAGE_WV(R1_OFF, kb4, 12);                           // q3 -> R1
        __builtin_amdgcn_sched_barrier(0);

        WAIT_VM(4);                                                   // q2 ready (q3 may remain)
        DOT_Q(2, R0_OFF);

        // V batch 0 issued now (younger than q3) -> rides through dot q3 + softmax
        float va[8];
        #pragma unroll
        for (int i = 0; i < 8; ++i) va[i] = vptr[(size_t)i * DN];
        __builtin_amdgcn_sched_barrier(0);
        WAIT_VM(8);                                                   // q3 ready (va(8) younger)
        DOT_Q(3, R1_OFF);

        // ---- softmax over the 16 queries (thread-local, k = krow0 + tid) ----
        float m = s[0];
        #pragma unroll
        for (int q = 1; q < QN; ++q) m = fmaxf(m, s[q]);
        float sum = 0.f;
        #pragma unroll
        for (int q = 0; q < QN; ++q) { s[q] = __expf(s[q] - m); sum += s[q]; }
        const float inv = 1.0f / sum;
        {
            float* ab = attn + (size_t)b * QN * KTOT + krow0 + tid;
            #pragma unroll
            for (int q = 0; q < QN; ++q) {
                const float a = s[q] * inv;
                __builtin_nontemporal_store(a, ab + (size_t)q * KTOT);
                smem[AW + q * 64 + lane] = a;        // own slice; dot-q3 reads already retired
            }
        }

        // ---- PV: U[q][lane=d] += a[q][k] * v[k][d]; wave owns 64 k-rows ----
        #pragma unroll 1
        for (int kk = 0; kk < 64; kk += 8) {
            float vb[8];
            const int nxt = kk + 8;
            if (nxt < 64) {
                #pragma unroll
                for (int i = 0; i < 8; ++i) vb[i] = vptr[(size_t)(nxt + i) * DN];
            }
            #pragma unroll
            for (int kq = 0; kq < 8; kq += 4) {
                #pragma unroll
                for (int q = 0; q < QN; ++q) {
                    const float4 av = *reinterpret_cast<const float4*>(
                        &smem[AW + q * 64 + kk + kq]);              // uniform broadcast
                    U[q] = fmaf(av.x, va[kq + 0], U[q]);
                    U[q] = fmaf(av.y, va[kq + 1], U[q]);
                    U[q] = fmaf(av.z, va[kq + 2], U[q]);
                    U[q] = fmaf(av.w, va[kq + 3], U[q]);
                }
            }
            #pragma unroll
            for (int i = 0; i < 8; ++i) va[i] = vb[i];
        }

        // next tile's q0,q1 issued at PV end (r9 schedule; hoist was tested r11: neutral)
        if (t + 1 < ntiles) {
            LGKM0();
            STAGE_WV(R0_OFF, kb4n, 0);
            STAGE_WV(R1_OFF, kb4n, 4);
            __builtin_amdgcn_sched_barrier(0);
        }
    }

    // ---- block reduction: U across 4 waves (R0 region) ----
    __syncthreads();                                   // full drain (outside main loop)
    #pragma unroll
    for (int q = 0; q < QN; ++q)
        smem[R0_OFF + (wv * QN + q) * DN + lane] = U[q];
    __syncthreads();

    {
        const int q = tid >> 4, d0 = (tid & 15) * 4;
        const float4 r0 = *reinterpret_cast<const float4*>(&smem[R0_OFF + (0 * QN + q) * DN + d0]);
        const float4 r1 = *reinterpret_cast<const float4*>(&smem[R0_OFF + (1 * QN + q) * DN + d0]);
        const float4 r2 = *reinterpret_cast<const float4*>(&smem[R0_OFF + (2 * QN + q) * DN + d0]);
        const float4 r3 = *reinterpret_cast<const float4*>(&smem[R0_OFF + (3 * QN + q) * DN + d0]);
        float4 rs;
        rs.x = r0.x + r1.x + r2.x + r3.x;
        rs.y = r0.y + r1.y + r2.y + r3.y;
        rs.z = r0.z + r1.z + r2.z + r3.z;
        rs.w = r0.w + r1.w + r2.w + r3.w;
        *reinterpret_cast<float4*>(
            &upart[(((size_t)b * NCH + c) * QN + q) * DN + d0]) = rs;
    }
}

// ------------- Finalize: norm from attn matrix; out = sum_c U / (norm + eps) -----------
// grid (8,16). norm[b][q] = sum_k attn[b][q][k] — the 33MB re-read is L2/L3-resident
// (just written) and replaces the fused kernel's nacc registers + normp machinery.
__global__ __launch_bounds__(256) void k3_fin(
    const float* __restrict__ attn, const float* __restrict__ upart,
    float* __restrict__ out, int NCH)
{
    const int b = blockIdx.x, q = blockIdx.y;
    const int tid = threadIdx.x;
    const int wv = tid >> 6, lane = tid & 63;

    // norm: coalesced float4 sweep of this (b,q) attn row
    const float4* ap = reinterpret_cast<const float4*>(attn + ((size_t)b * QN + q) * KTOT);
    float nv = 0.f;
    #pragma unroll 4
    for (int i = tid; i < KTOT / 4; i += 256) {
        const float4 a = ap[i];
        nv += (a.x + a.y) + (a.z + a.w);
    }
    #pragma unroll
    for (int off = 1; off < 64; off <<= 1) nv += __shfl_xor(nv, off, 64);
    __shared__ float nred[4];
    if (lane == 0) nred[wv] = nv;

    // U: wave wv strides chunks, lane = d (coalesced)
    float acc = 0.f;
    for (int c = wv; c < NCH; c += 4)
        acc += upart[(((size_t)b * NCH + c) * QN + q) * DN + lane];
    __shared__ float ured[4][DN];
    ured[wv][lane] = acc;
    __syncthreads();

    if (tid < DN) {
        const float n   = nred[0] + nred[1] + nred[2] + nred[3];
        const float inv = 1.0f / (n + 1e-8f);
        const float u   = ured[0][tid] + ured[1][tid] + ured[2][tid] + ured[3][tid];
        out[((size_t)b * QN + q) * DN + tid] = u * inv;
    }
}

extern "C" void kernel_launch(void* const* d_in, const int* in_sizes, int n_in,
                              void* d_out, int out_size, void* d_ws, size_t ws_size,
                              hipStream_t stream)
{
    const float* query = (const float*)d_in[0];
    const float* key   = (const float*)d_in[1];
    const float* value = (const float*)d_in[2];

    float* out  = (float*)d_out;                          // [8,16,64]
    float* attn = (float*)d_out + (size_t)BN * QN * DN;   // [8,1,16,65536]

    int NCH = 128;                                        // 1024 blocks (round-9 proven)
    while (NCH > 8 && (size_t)BN * NCH * QN * DN * 4 > ws_size) NCH >>= 1;
    const int ntiles = (KTOT / NCH) / TILE;

    float* upart = (float*)d_ws;                          // [8][NCH][16][64]

    fused_attn<<<dim3(NCH, BN), 256, 0, stream>>>(query, key, value, attn,
                                                  upart, NCH, ntiles);
    k3_fin   <<<dim3(BN, QN), 256, 0, stream>>>(attn, upart, out, NCH);
}